// Round 4
// baseline (1551.463 us; speedup 1.0000x reference)
//
#include <hip/hip_runtime.h>

#define Bb 8
#define Nn 512
#define Ee 1024
#define Hh 128
#define Tt 8
#define FPAD 132   // fuse_gru X rows: rows stride ≡4 mod 32 banks, conflict-free for r=lane>>3
#define EPAD 136   // edge_mp sEmb: rows stride ≡8 mod 32, conflict-free for 4-edge groups

__device__ __forceinline__ float sigm(float x){ return 1.0f/(1.0f + __expf(-x)); }
__device__ __forceinline__ float tanh_fast(float x){ return 2.0f/(1.0f + __expf(-2.0f*x)) - 1.0f; }

__device__ __forceinline__ void fma4(float* acc, float4 x, float4 w0, float4 w1, float4 w2, float4 w3){
  acc[0] += x.x*w0.x + x.y*w1.x + x.z*w2.x + x.w*w3.x;
  acc[1] += x.x*w0.y + x.y*w1.y + x.z*w2.y + x.w*w3.y;
  acc[2] += x.x*w0.z + x.y*w1.z + x.z*w2.z + x.w*w3.z;
  acc[3] += x.x*w0.w + x.y*w1.w + x.z*w2.w + x.w*w3.w;
}

// Extract src/tgt indices from the dense one-hot incidence matrices.
__global__ void k_extract(const float4* __restrict__ n2e, const float4* __restrict__ e2n,
                          int* __restrict__ src, int* __restrict__ tgt){
  const int total1 = Bb*Ee*Nn/4;
  for (int i = blockIdx.x*blockDim.x + threadIdx.x; i < total1; i += gridDim.x*blockDim.x){
    float4 v = n2e[i];
    if (v.x!=0.f || v.y!=0.f || v.z!=0.f || v.w!=0.f){
      int base = i*4;
      int row = base >> 9;        // b*E + e   (N = 512)
      int n   = base & 511;
      if (v.x!=0.f) src[row] = n;
      if (v.y!=0.f) src[row] = n+1;
      if (v.z!=0.f) src[row] = n+2;
      if (v.w!=0.f) src[row] = n+3;
    }
  }
  const int total2 = Bb*Nn*Ee/4;
  for (int i = blockIdx.x*blockDim.x + threadIdx.x; i < total2; i += gridDim.x*blockDim.x){
    float4 v = e2n[i];
    if (v.x!=0.f || v.y!=0.f || v.z!=0.f || v.w!=0.f){
      int base = i*4;
      int row = base >> 10;       // b*N + n   (E = 1024)
      int e   = base & 1023;
      int b = row >> 9, n = row & 511;
      int* tp = tgt + b*Ee;
      if (v.x!=0.f) tp[e]   = n;
      if (v.y!=0.f) tp[e+1] = n;
      if (v.z!=0.f) tp[e+2] = n;
      if (v.w!=0.f) tp[e+3] = n;
    }
  }
}

// Transpose edge weights: W[t][h][d] -> WT[t][d][h]
__global__ void k_transW(const float* __restrict__ W, float* __restrict__ WT){
  int i = blockIdx.x*blockDim.x + threadIdx.x;
  if (i >= Tt*Hh*Hh) return;
  int t = i >> 14;
  int h = (i >> 7) & 127;
  int d = i & 127;
  WT[(t*Hh + d)*Hh + h] = W[i];
}

// Fold Wf: af = fw@(Wa+Wd) + bw@(Wb-Wd) + (fw*bw)@Wc   -> Ff[384][128]
__global__ void k_prep(const float* __restrict__ Wf, float* __restrict__ Ff){
  int i = blockIdx.x*blockDim.x + threadIdx.x;
  if (i >= 384*Hh) return;
  int r = i >> 7, c = i & 127;
  float v;
  if (r < 128)      v = Wf[r*Hh + c] + Wf[(r+384)*Hh + c];
  else if (r < 256) v = Wf[r*Hh + c] - Wf[(r+256)*Hh + c];
  else              v = Wf[r*Hh + c];
  Ff[i] = v;
}

// Per-graph counting sort of edges by type.
__global__ void k_sort(const int* __restrict__ ev, int* __restrict__ order, int* __restrict__ offs){
  __shared__ int cnt[Tt], offs_s[Tt+1], pos[Tt];
  int b = blockIdx.x, tid = threadIdx.x;
  if (tid < Tt) cnt[tid] = 0;
  __syncthreads();
  for (int e = tid; e < Ee; e += blockDim.x) atomicAdd(&cnt[ev[b*Ee+e]], 1);
  __syncthreads();
  if (tid == 0){ offs_s[0]=0; for (int t=0;t<Tt;t++) offs_s[t+1]=offs_s[t]+cnt[t]; }
  __syncthreads();
  if (tid < Tt) pos[tid] = offs_s[tid];
  if (tid < Tt+1) offs[b*(Tt+1)+tid] = offs_s[tid];
  __syncthreads();
  for (int e = tid; e < Ee; e += blockDim.x){
    int t = ev[b*Ee+e];
    int p = atomicAdd(&pos[t], 1);
    order[b*Ee + p] = e;
  }
}

// ------------- edge message passing v4: register-pipelined W prefetch -------------
// block = (b, t, dir) x chunk; 256 threads; thread = 4 edges x 4 cols.
__global__ __launch_bounds__(256, 2) void k_edge_mp(
    const float* __restrict__ h, const float* __restrict__ WT,
    const int* __restrict__ order, const int* __restrict__ offs,
    const int* __restrict__ src, const int* __restrict__ tgt,
    float* __restrict__ bw, float* __restrict__ fw)
{
  int x = blockIdx.x;
  int dir = x & 1, bt = x >> 1, t = bt & 7, b = bt >> 3;
  int beg = offs[b*(Tt+1)+t], end = offs[b*(Tt+1)+t+1];
  int chunk0 = beg + blockIdx.y*32;
  if (chunk0 >= end) return;
  const int* gI = dir ? tgt : src;
  const int* sI = dir ? src : tgt;
  float* out = dir ? fw : bw;

  __shared__ float sEmb[32][EPAD];
  __shared__ int sNode[32];
  int tid = threadIdx.x, lane = tid & 63, w = tid >> 6;
  int e0 = (lane >> 3)*4;
  int c0 = w*32 + (lane & 7)*4;
  const float* __restrict__ Wg = WT + t*Hh*Hh + c0;

  for (int chunk = chunk0; chunk < end; chunk += gridDim.y*32){
    int ne = min(32, end - chunk);
    __syncthreads();                    // protect sEmb/sNode from prev iteration readers
    {
      int ir = tid >> 5, k0 = (tid & 31)*4;
      #pragma unroll
      for (int rr = 0; rr < 4; ++rr){
        int e = ir + rr*8;
        float4 v = {0.f,0.f,0.f,0.f};
        if (e < ne){
          int eid = order[b*Ee + chunk + e];
          v = *(const float4*)&h[(size_t)(b*Nn + gI[b*Ee + eid])*Hh + k0];
        }
        *(float4*)&sEmb[e][k0] = v;
      }
      if (tid < 32){
        int nd = -1;
        if (tid < ne){ int eid = order[b*Ee + chunk + tid]; nd = sI[b*Ee + eid]; }
        sNode[tid] = nd;
      }
    }
    __syncthreads();

    // pipelined K=128 in 16 stages of 8 k-rows, double-buffered W + X
    float acc[4][4] = {};
    float4 wb[2][8], xe[2][4][2];
    #pragma unroll
    for (int j = 0; j < 8; ++j) wb[0][j] = *(const float4*)&Wg[j*Hh];
    #pragma unroll
    for (int je = 0; je < 4; ++je){
      xe[0][je][0] = *(const float4*)&sEmb[e0+je][0];
      xe[0][je][1] = *(const float4*)&sEmb[e0+je][4];
    }
    #pragma unroll
    for (int s = 0; s < 16; ++s){
      const int cur = s & 1, nxt = cur ^ 1;
      if (s < 15){
        #pragma unroll
        for (int j = 0; j < 8; ++j) wb[nxt][j] = *(const float4*)&Wg[((s+1)*8 + j)*Hh];
        #pragma unroll
        for (int je = 0; je < 4; ++je){
          xe[nxt][je][0] = *(const float4*)&sEmb[e0+je][(s+1)*8];
          xe[nxt][je][1] = *(const float4*)&sEmb[e0+je][(s+1)*8 + 4];
        }
      }
      #pragma unroll
      for (int je = 0; je < 4; ++je){
        fma4(acc[je], xe[cur][je][0], wb[cur][0], wb[cur][1], wb[cur][2], wb[cur][3]);
        fma4(acc[je], xe[cur][je][1], wb[cur][4], wb[cur][5], wb[cur][6], wb[cur][7]);
      }
    }

    #pragma unroll
    for (int j = 0; j < 4; ++j){
      int node = sNode[e0+j];
      if (node >= 0){
        float* op = out + (size_t)(b*Nn + node)*Hh + c0;
        atomicAdd(op+0, acc[j][0]);
        atomicAdd(op+1, acc[j][1]);
        atomicAdd(op+2, acc[j][2]);
        atomicAdd(op+3, acc[j][3]);
      }
    }
  }
}

// ------------- fused GatedFusion + GRU v4: register-pipelined W prefetch -------------
// 512 blocks x 256 threads; block = 8 rows x 128 cols; thread = 1 row x 4 cols.

// single-W section, K=128: 8 stages of 16 k-rows, double-buffered.
__device__ __forceinline__ void gemm_sec(const float (*X)[FPAD], int r,
                                         const float* __restrict__ Wg, float* acc){
  float4 wb[2][16], xb[2][4];
  #pragma unroll
  for (int j = 0; j < 16; ++j) wb[0][j] = *(const float4*)&Wg[j*Hh];
  #pragma unroll
  for (int q = 0; q < 4; ++q) xb[0][q] = *(const float4*)&X[r][q*4];
  #pragma unroll
  for (int s = 0; s < 8; ++s){
    const int cur = s & 1, nxt = cur ^ 1;
    if (s < 7){
      #pragma unroll
      for (int j = 0; j < 16; ++j) wb[nxt][j] = *(const float4*)&Wg[((s+1)*16 + j)*Hh];
      #pragma unroll
      for (int q = 0; q < 4; ++q) xb[nxt][q] = *(const float4*)&X[r][(s+1)*16 + q*4];
    }
    #pragma unroll
    for (int q = 0; q < 4; ++q)
      fma4(acc, xb[cur][q], wb[cur][4*q+0], wb[cur][4*q+1], wb[cur][4*q+2], wb[cur][4*q+3]);
  }
}

// (A*B)@W section, K=128
__device__ __forceinline__ void gemm_prod(const float (*A)[FPAD], const float (*B)[FPAD], int r,
                                          const float* __restrict__ Wg, float* acc){
  float4 wb[2][16], xa[2][4], xc[2][4];
  #pragma unroll
  for (int j = 0; j < 16; ++j) wb[0][j] = *(const float4*)&Wg[j*Hh];
  #pragma unroll
  for (int q = 0; q < 4; ++q){ xa[0][q] = *(const float4*)&A[r][q*4]; xc[0][q] = *(const float4*)&B[r][q*4]; }
  #pragma unroll
  for (int s = 0; s < 8; ++s){
    const int cur = s & 1, nxt = cur ^ 1;
    if (s < 7){
      #pragma unroll
      for (int j = 0; j < 16; ++j) wb[nxt][j] = *(const float4*)&Wg[((s+1)*16 + j)*Hh];
      #pragma unroll
      for (int q = 0; q < 4; ++q){
        xa[nxt][q] = *(const float4*)&A[r][(s+1)*16 + q*4];
        xc[nxt][q] = *(const float4*)&B[r][(s+1)*16 + q*4];
      }
    }
    #pragma unroll
    for (int q = 0; q < 4; ++q){
      float4 a = xa[cur][q], c = xc[cur][q];
      float4 xv = make_float4(a.x*c.x, a.y*c.y, a.z*c.z, a.w*c.w);
      fma4(acc, xv, wb[cur][4*q+0], wb[cur][4*q+1], wb[cur][4*q+2], wb[cur][4*q+3]);
    }
  }
}

// X@Wa and X@Wc simultaneously, K=128: 16 stages of 8 k-rows.
__device__ __forceinline__ void gemm2(const float (*X)[FPAD], int r,
                                      const float* __restrict__ Wa, const float* __restrict__ Wc,
                                      float* acc1, float* acc2){
  float4 wa[2][8], wc[2][8], xb[2][2];
  #pragma unroll
  for (int j = 0; j < 8; ++j){ wa[0][j] = *(const float4*)&Wa[j*Hh]; wc[0][j] = *(const float4*)&Wc[j*Hh]; }
  xb[0][0] = *(const float4*)&X[r][0];
  xb[0][1] = *(const float4*)&X[r][4];
  #pragma unroll
  for (int s = 0; s < 16; ++s){
    const int cur = s & 1, nxt = cur ^ 1;
    if (s < 15){
      #pragma unroll
      for (int j = 0; j < 8; ++j){
        wa[nxt][j] = *(const float4*)&Wa[((s+1)*8 + j)*Hh];
        wc[nxt][j] = *(const float4*)&Wc[((s+1)*8 + j)*Hh];
      }
      xb[nxt][0] = *(const float4*)&X[r][(s+1)*8];
      xb[nxt][1] = *(const float4*)&X[r][(s+1)*8 + 4];
    }
    fma4(acc1, xb[cur][0], wa[cur][0], wa[cur][1], wa[cur][2], wa[cur][3]);
    fma4(acc1, xb[cur][1], wa[cur][4], wa[cur][5], wa[cur][6], wa[cur][7]);
    fma4(acc2, xb[cur][0], wc[cur][0], wc[cur][1], wc[cur][2], wc[cur][3]);
    fma4(acc2, xb[cur][1], wc[cur][4], wc[cur][5], wc[cur][6], wc[cur][7]);
  }
}

__global__ __launch_bounds__(256, 2) void k_fuse_gru(
    const float* __restrict__ hin, const float* __restrict__ fw, const float* __restrict__ bw,
    const float* __restrict__ Ff, const float* __restrict__ bfv,
    const float* __restrict__ Wz, const float* __restrict__ Wr, const float* __restrict__ Wt,
    float* __restrict__ hout, float* __restrict__ zf, float* __restrict__ zb)
{
  __shared__ float sF[8][FPAD];   // fw -> agg
  __shared__ float sS[8][FPAD];   // bw -> r*h
  __shared__ float sH[8][FPAD];   // h
  int tid  = threadIdx.x;
  int row0 = blockIdx.x * 8;
  int lane = tid & 63, w = tid >> 6;
  int r    = lane >> 3;
  int c0   = w*32 + (lane & 7)*4;

  {
    int ir = tid >> 5, k0 = (tid & 31)*4;
    size_t g = (size_t)(row0 + ir)*Hh + k0;
    *(float4*)&sF[ir][k0] = *(const float4*)&fw[g];
    *(float4*)&sS[ir][k0] = *(const float4*)&bw[g];
    *(float4*)&sH[ir][k0] = *(const float4*)&hin[g];
  }
  float4 bias = *(const float4*)&bfv[c0];
  __syncthreads();

  // ---- P1: af = fw@F[0:128] + bw@F[128:256] + (fw*bw)@F[256:384] ----
  float af[4] = {0,0,0,0};
  gemm_sec (sF, r, Ff + c0,              af);
  gemm_sec (sS, r, Ff + 128*Hh + c0,     af);
  gemm_prod(sF, sS, r, Ff + 256*Hh + c0, af);

  float agv[4];
  {
    float bb[4] = {bias.x, bias.y, bias.z, bias.w};
    #pragma unroll
    for (int j = 0; j < 4; ++j){
      float z = sigm(af[j] + bb[j]);
      agv[j] = (1.0f - z)*sF[r][c0+j] + z*sS[r][c0+j];
    }
  }
  __syncthreads();                              // all P1 reads of sF/sS done
  *(float4*)&sF[r][c0] = make_float4(agv[0], agv[1], agv[2], agv[3]);
  __syncthreads();                              // agg visible

  // ---- P2: az = [h|agg]@Wz, ar = [h|agg]@Wr  (X shared) ----
  float az[4] = {0,0,0,0}, ar[4] = {0,0,0,0};
  gemm2(sH, r, Wz + c0,          Wr + c0,          az, ar);
  gemm2(sF, r, Wz + 128*Hh + c0, Wr + 128*Hh + c0, az, ar);

  float zz[4];
  {
    float rh[4];
    #pragma unroll
    for (int j = 0; j < 4; ++j){
      zz[j] = sigm(az[j]);
      rh[j] = sigm(ar[j]) * sH[r][c0+j];
    }
    *(float4*)&sS[r][c0] = make_float4(rh[0], rh[1], rh[2], rh[3]);
  }
  __syncthreads();                              // rh visible

  // ---- P3: at = [rh|agg]@Wt ----
  float at[4] = {0,0,0,0};
  gemm_sec(sS, r, Wt + c0,          at);
  gemm_sec(sF, r, Wt + 128*Hh + c0, at);

  float o[4];
  #pragma unroll
  for (int j = 0; j < 4; ++j){
    float t = tanh_fast(at[j]);
    o[j] = (1.0f - zz[j])*sH[r][c0+j] + zz[j]*t;
  }
  *(float4*)&hout[(size_t)(row0 + r)*Hh + c0] = make_float4(o[0], o[1], o[2], o[3]);

  // zero fw/bw slices for the next hop (replaces per-hop memsets)
  {
    int ir = tid >> 5, k0 = (tid & 31)*4;
    size_t g = (size_t)(row0 + ir)*Hh + k0;
    float4 zv = {0.f,0.f,0.f,0.f};
    *(float4*)&zf[g] = zv;
    *(float4*)&zb[g] = zv;
  }
}

extern "C" void kernel_launch(void* const* d_in, const int* in_sizes, int n_in,
                              void* d_out, int out_size, void* d_ws, size_t ws_size,
                              hipStream_t stream){
  const float* node_feature = (const float*)d_in[0];
  const int*   edge_vec     = (const int*)d_in[1];
  const float* n2e          = (const float*)d_in[2];
  const float* e2n          = (const float*)d_in[3];
  const float* Wtensor      = (const float*)d_in[4];
  const float* Wz           = (const float*)d_in[5];
  const float* Wr           = (const float*)d_in[6];
  const float* Wt           = (const float*)d_in[7];
  const float* Wf           = (const float*)d_in[8];
  const float* bf           = (const float*)d_in[9];
  float* out = (float*)d_out;

  char* p = (char*)d_ws;
  int* src   = (int*)p; p += Bb*Ee*4;
  int* tgt   = (int*)p; p += Bb*Ee*4;
  int* order = (int*)p; p += Bb*Ee*4;
  int* offs  = (int*)p; p += 4096;
  float* WT  = (float*)p; p += (size_t)Tt*Hh*Hh*4;
  float* Ff  = (float*)p; p += (size_t)384*Hh*4;
  float* bwp = (float*)p; p += (size_t)Bb*Nn*Hh*4;
  float* fwp = (float*)p; p += (size_t)Bb*Nn*Hh*4;
  float* h1  = (float*)p; p += (size_t)Bb*Nn*Hh*4;

  k_extract<<<1024, 256, 0, stream>>>((const float4*)n2e, (const float4*)e2n, src, tgt);
  k_transW<<<(Tt*Hh*Hh + 255)/256, 256, 0, stream>>>(Wtensor, WT);
  k_prep<<<(384*Hh + 255)/256, 256, 0, stream>>>(Wf, Ff);
  k_sort<<<Bb, 256, 0, stream>>>(edge_vec, order, offs);
  hipMemsetAsync(bwp, 0, (size_t)2*Bb*Nn*Hh*4, stream);   // bw+fw zero (hops re-zero in epilogue)

  const float* hin = node_feature;
  float* houts[3] = { out, h1, out };
  for (int hop = 0; hop < 3; ++hop){
    k_edge_mp<<<dim3(Bb*Tt*2, 4), 256, 0, stream>>>(hin, WT, order, offs, src, tgt, bwp, fwp);
    k_fuse_gru<<<(Bb*Nn)/8, 256, 0, stream>>>(hin, fwp, bwp, Ff, bf, Wz, Wr, Wt, houts[hop], fwp, bwp);
    hin = houts[hop];
  }
}